// Round 9
// baseline (55.455 us; speedup 1.0000x reference)
//
#include <hip/hip_runtime.h>
#include <math.h>

#define NB   64
#define D    256
#define HW   25
#define TRI  32896         // 256*257/2
#define TS   64            // tile size (i and j)
#define PSTR 68            // padded p-row stride of transposed LDS (floats)
#define MAGIC 0x13579BDF
#define SLOT_FLOATS (NB * 4 * 4 * TS)   // 65536 floats = 256 KB

// tile id t (0..9) -> band pair (bi<=bj) of 4 bands
__device__ __forceinline__ void tile_bands(int t, int& bi, int& bj) {
    bi = (t < 4) ? 0 : (t < 7) ? 1 : (t < 9) ? 2 : 3;
    const int o4 = (bi == 0) ? 0 : (bi == 1) ? 4 : (bi == 2) ? 7 : 9;
    bj = bi + (t - o4);
}

// ---------------------------------------------------------------------------
// Single fused kernel, proven R6 geometry: 640 blocks (64 b x 10 triu tiles),
// 256 threads = 16(tx:j) x 16(ty:i), thread owns 4x4 of
//   e(i,j) = sum_p |f_i+f_j| - |f_i-f_j|   (kept in registers throughout).
//
// Phase 1: partial row-sum vectors -> collision-free d_ws slots
//   (band bi slot bj-bi from i-partials; band bj slot 4-bj+bi from j-partials;
//    every (b,band) gets slots 0..3 written exactly once).
// Handshake (batch-local, replay-safe, no grid sync):
//   writer t stores MAGIC to flags[b][t][W] for W=0..9 after a release fence;
//   waiter t polls flags[b][tw][t] (tw=0..9), resets each to 0 (sole reader).
//   All 640 blocks co-resident (22.8 KB LDS -> 7 blocks/CU) => no deadlock.
//   Poison 0xAAAAAAAA != MAGIC and readers reset to 0 => replay-safe.
// Phase 2: rs = sum of the band's 4 slots; write final centered value once:
//   out = sc*(acc - (rs_i + rs_j)/256),  sc = 0.5*exp(T).  Raw e never hits
//   global memory.
// ---------------------------------------------------------------------------
__global__ __launch_bounds__(256) void fused_kernel(const float* __restrict__ feat,
                                                    const float* __restrict__ temp,
                                                    float* __restrict__ rsp,
                                                    int* __restrict__ flags,
                                                    float* __restrict__ out) {
    __shared__ __align__(16) float as[HW * PSTR];
    __shared__ __align__(16) float bs[HW * PSTR];
    __shared__ float red[2][TS][17];
    __shared__ float rsum[2][TS];

    const int tid = threadIdx.x;
    const int blk = blockIdx.x;
    const int b   = blk / 10;
    const int t   = blk - b * 10;
    int bi, bj; tile_bands(t, bi, bj);
    const int ibase = bi * TS, jbase = bj * TS;
    const bool diag = (bi == bj);

    const float* fb = feat + (size_t)b * D * HW;

    // stage tile rows, transposed (coalesced r-major global reads)
    for (int idx = tid; idx < TS * HW; idx += 256) {
        int r = idx / HW;
        int p = idx - r * HW;
        as[p * PSTR + r] = fb[(ibase + r) * HW + p];
    }
    if (!diag) {
        for (int idx = tid; idx < TS * HW; idx += 256) {
            int r = idx / HW;
            int p = idx - r * HW;
            bs[p * PSTR + r] = fb[(jbase + r) * HW + p];
        }
    }
    __syncthreads();

    const float* bsp = diag ? as : bs;
    const int tx = tid & 15;
    const int ty = tid >> 4;

    float acc[4][4] = {{0.f}};
#pragma unroll 5
    for (int p = 0; p < HW; ++p) {
        float4 av = *reinterpret_cast<const float4*>(&as[p * PSTR + ty * 4]);
        float4 bv = *reinterpret_cast<const float4*>(&bsp[p * PSTR + tx * 4]);
        float a4[4] = {av.x, av.y, av.z, av.w};
        float b4[4] = {bv.x, bv.y, bv.z, bv.w};
#pragma unroll
        for (int r = 0; r < 4; ++r)
#pragma unroll
            for (int q = 0; q < 4; ++q)
                acc[r][q] += fabsf(a4[r] + b4[q]) - fabsf(a4[r] - b4[q]);
    }

    // -------- phase 1: partial row vectors -> slots --------
    float pi[4];
#pragma unroll
    for (int r = 0; r < 4; ++r) pi[r] = acc[r][0] + acc[r][1] + acc[r][2] + acc[r][3];
#pragma unroll
    for (int r = 0; r < 4; ++r) red[0][ty * 4 + r][tx] = pi[r];
    if (!diag) {
        float pj[4];
#pragma unroll
        for (int q = 0; q < 4; ++q) pj[q] = acc[0][q] + acc[1][q] + acc[2][q] + acc[3][q];
#pragma unroll
        for (int q = 0; q < 4; ++q) red[1][tx * 4 + q][ty] = pj[q];
    }
    __syncthreads();

    if (tid < TS) {
        float si = 0.f;
#pragma unroll
        for (int x = 0; x < 16; ++x) si += red[0][tid][x];
        rsp[((b * 4 + bi) * 4 + (bj - bi)) * TS + tid] = si;
    } else if (tid < 2 * TS && !diag) {
        const int il = tid - TS;
        float sj = 0.f;
#pragma unroll
        for (int x = 0; x < 16; ++x) sj += red[1][il][x];
        rsp[((b * 4 + bj) * 4 + (4 - bj + bi)) * TS + il] = sj;
    }

    // -------- handshake: arrive --------
    __builtin_amdgcn_fence(__ATOMIC_RELEASE, "agent");
    __syncthreads();   // all slot stores + fence done before any flag store
    if (tid < 10) {
        __hip_atomic_store(&flags[(b * 10 + t) * 10 + tid], MAGIC,
                           __ATOMIC_RELAXED, __HIP_MEMORY_SCOPE_AGENT);
    }
    // -------- handshake: wait (waiter column t; reset own column) --------
    if (tid < 10) {
        int* w = &flags[(b * 10 + tid) * 10 + t];
        while (__hip_atomic_load(w, __ATOMIC_RELAXED, __HIP_MEMORY_SCOPE_AGENT) != MAGIC)
            __builtin_amdgcn_s_sleep(8);
        __hip_atomic_store(w, 0, __ATOMIC_RELAXED, __HIP_MEMORY_SCOPE_AGENT);
    }
    __syncthreads();
    __builtin_amdgcn_fence(__ATOMIC_ACQUIRE, "agent");

    // -------- phase 2: gather full row sums for the two bands --------
    if (tid < TS) {
        float s = 0.f;
#pragma unroll
        for (int sl = 0; sl < 4; ++sl) s += rsp[((b * 4 + bi) * 4 + sl) * TS + tid];
        rsum[0][tid] = s;
    } else if (tid < 2 * TS) {
        const int il = tid - TS;
        float s = 0.f;
#pragma unroll
        for (int sl = 0; sl < 4; ++sl) s += rsp[((b * 4 + bj) * 4 + sl) * TS + il];
        rsum[1][il] = s;
    }
    __syncthreads();

    const float sc = 0.5f * expf(temp[0]);
    float* ob = out + (size_t)b * TRI;
    if (diag) {
#pragma unroll
        for (int r = 0; r < 4; ++r) {
            const int i = ibase + ty * 4 + r;
            const int rowoff = (i * (513 - i)) >> 1;
            const float ri = rsum[0][ty * 4 + r];
#pragma unroll
            for (int q = 0; q < 4; ++q) {
                const int j = jbase + tx * 4 + q;
                if (j >= i)
                    ob[rowoff + (j - i)] =
                        sc * (acc[r][q] - (ri + rsum[1][tx * 4 + q]) * (1.0f / 256.0f));
            }
        }
    } else {
#pragma unroll
        for (int r = 0; r < 4; ++r) {
            const int i = ibase + ty * 4 + r;
            const int rowoff = (i * (513 - i)) >> 1;
            const float ri = rsum[0][ty * 4 + r];
#pragma unroll
            for (int q = 0; q < 4; ++q) {
                const int j = jbase + tx * 4 + q;
                ob[rowoff + (j - i)] =
                    sc * (acc[r][q] - (ri + rsum[1][tx * 4 + q]) * (1.0f / 256.0f));
            }
        }
    }
}

extern "C" void kernel_launch(void* const* d_in, const int* in_sizes, int n_in,
                              void* d_out, int out_size, void* d_ws, size_t ws_size,
                              hipStream_t stream) {
    const float* feat = (const float*)d_in[0];
    const float* temp = (const float*)d_in[1];
    float* out   = (float*)d_out;
    float* rsp   = (float*)d_ws;                         // 256 KB slot vectors
    int*   flags = (int*)((char*)d_ws + SLOT_FLOATS * sizeof(float));  // 64*10*10 ints

    fused_kernel<<<NB * 10, 256, 0, stream>>>(feat, temp, rsp, flags, out);
}

// Round 10
// 28.089 us; speedup vs baseline: 1.9742x; 1.9742x over previous
//
#include <hip/hip_runtime.h>
#include <math.h>

#define NB   64
#define D    256
#define HW   25
#define TRI  32896         // 256*257/2
#define TS   64            // tile size (i and j)
#define PSTR 68            // padded p-row stride of transposed LDS (floats)

// tile id t (0..9) -> band pair (bi<=bj) of 4 bands
__device__ __forceinline__ void tile_bands(int t, int& bi, int& bj) {
    bi = (t < 4) ? 0 : (t < 7) ? 1 : (t < 9) ? 2 : 3;
    const int o4 = (bi == 0) ? 0 : (bi == 1) ? 4 : (bi == 2) ? 7 : 9;
    bj = bi + (t - o4);
}

// ---------------------------------------------------------------------------
// K1: one 64x64 triu tile per block (64 b x 10 tiles = 640 blocks), but now
// 512 threads = 16(tx:j) x 32(ty:i), each thread a 2x4 sub-tile of
//   e(i,j) = sum_p |f_i+f_j| - |f_i-f_j|.
// 512 thr = 8 waves/block -> 20 waves/CU (5/SIMD) for latency hiding (R9
// post-mortem: 256-thr version was ~70% stalled at 2.5 waves/SIMD).
// Raw e -> d_out triu; partial row-sum vectors -> collision-free d_ws slots
// (band bi slot bj-bi from i-partials; band bj slot 4-bj+bi from j-partials).
// ---------------------------------------------------------------------------
__global__ __launch_bounds__(512) void tile_kernel(const float* __restrict__ feat,
                                                   float* __restrict__ rsp,
                                                   float* __restrict__ out) {
    __shared__ __align__(16) float as[HW * PSTR];
    __shared__ __align__(16) float bs[HW * PSTR];
    __shared__ float red0[TS][17];   // i-partials, reduced over tx (16)
    __shared__ float red1[TS][33];   // j-partials, reduced over ty (32)

    const int tid = threadIdx.x;
    const int blk = blockIdx.x;
    const int b   = blk / 10;
    const int t   = blk - b * 10;
    int bi, bj; tile_bands(t, bi, bj);
    const int ibase = bi * TS, jbase = bj * TS;
    const bool diag = (bi == bj);

    const float* fb = feat + (size_t)b * D * HW;

    // stage tile rows transposed (coalesced r-major global reads)
    for (int idx = tid; idx < TS * HW; idx += 512) {
        int r = idx / HW;
        int p = idx - r * HW;
        as[p * PSTR + r] = fb[(ibase + r) * HW + p];
    }
    if (!diag) {
        for (int idx = tid; idx < TS * HW; idx += 512) {
            int r = idx / HW;
            int p = idx - r * HW;
            bs[p * PSTR + r] = fb[(jbase + r) * HW + p];
        }
    }
    __syncthreads();

    const float* bsp = diag ? as : bs;
    const int tx = tid & 15;
    const int ty = tid >> 4;          // 0..31

    float acc[2][4] = {{0.f}};
#pragma unroll 5
    for (int p = 0; p < HW; ++p) {
        float2 av = *reinterpret_cast<const float2*>(&as[p * PSTR + ty * 2]);
        float4 bv = *reinterpret_cast<const float4*>(&bsp[p * PSTR + tx * 4]);
        float a2[2] = {av.x, av.y};
        float b4[4] = {bv.x, bv.y, bv.z, bv.w};
#pragma unroll
        for (int r = 0; r < 2; ++r)
#pragma unroll
            for (int q = 0; q < 4; ++q)
                acc[r][q] += fabsf(a2[r] + b4[q]) - fabsf(a2[r] - b4[q]);
    }

    // raw e -> d_out triu
    float* ob = out + (size_t)b * TRI;
    if (diag) {
#pragma unroll
        for (int r = 0; r < 2; ++r) {
            const int i = ibase + ty * 2 + r;
            const int rowoff = (i * (513 - i)) >> 1;
#pragma unroll
            for (int q = 0; q < 4; ++q) {
                const int j = jbase + tx * 4 + q;
                if (j >= i) ob[rowoff + (j - i)] = acc[r][q];
            }
        }
    } else {
#pragma unroll
        for (int r = 0; r < 2; ++r) {
            const int i = ibase + ty * 2 + r;
            const int rowoff = (i * (513 - i)) >> 1;
#pragma unroll
            for (int q = 0; q < 4; ++q) {
                const int j = jbase + tx * 4 + q;
                ob[rowoff + (j - i)] = acc[r][q];
            }
        }
    }

    // partial row vectors
    float pi[2];
#pragma unroll
    for (int r = 0; r < 2; ++r) pi[r] = acc[r][0] + acc[r][1] + acc[r][2] + acc[r][3];
#pragma unroll
    for (int r = 0; r < 2; ++r) red0[ty * 2 + r][tx] = pi[r];
    if (!diag) {
        float pj[4];
#pragma unroll
        for (int q = 0; q < 4; ++q) pj[q] = acc[0][q] + acc[1][q];
#pragma unroll
        for (int q = 0; q < 4; ++q) red1[tx * 4 + q][ty] = pj[q];
    }
    __syncthreads();

    if (tid < TS) {
        float si = 0.f;
#pragma unroll
        for (int x = 0; x < 16; ++x) si += red0[tid][x];
        rsp[((b * 4 + bi) * 4 + (bj - bi)) * TS + tid] = si;
    } else if (tid < 2 * TS && !diag) {
        const int c = tid - TS;
        float sj = 0.f;
#pragma unroll
        for (int x = 0; x < 32; ++x) sj += red1[c][x];
        rsp[((b * 4 + bj) * 4 + (4 - bj + bi)) * TS + c] = sj;
    }
}

// ---------------------------------------------------------------------------
// K2: same grid/tile map (L2 locality). Gather the two bands' slot vectors to
// full row sums, then in-place: out = sc*(e - (rs_i+rs_j)/256), sc=0.5*exp(T).
// ---------------------------------------------------------------------------
__global__ __launch_bounds__(512) void center_kernel(const float* __restrict__ temp,
                                                     const float* __restrict__ rsp,
                                                     float* __restrict__ out) {
    __shared__ float rsum[2][TS];

    const int tid = threadIdx.x;
    const int blk = blockIdx.x;
    const int b   = blk / 10;
    const int t   = blk - b * 10;
    int bi, bj; tile_bands(t, bi, bj);
    const int ibase = bi * TS, jbase = bj * TS;
    const bool diag = (bi == bj);

    if (tid < TS) {
        float s = 0.f;
#pragma unroll
        for (int sl = 0; sl < 4; ++sl) s += rsp[((b * 4 + bi) * 4 + sl) * TS + tid];
        rsum[0][tid] = s;
    } else if (tid < 2 * TS) {
        const int c = tid - TS;
        float s = 0.f;
#pragma unroll
        for (int sl = 0; sl < 4; ++sl) s += rsp[((b * 4 + bj) * 4 + sl) * TS + c];
        rsum[1][c] = s;
    }
    __syncthreads();

    const int tx = tid & 15;
    const int ty = tid >> 4;
    const float sc = 0.5f * expf(temp[0]);
    float* ob = out + (size_t)b * TRI;

#pragma unroll
    for (int r = 0; r < 2; ++r) {
        const int i = ibase + ty * 2 + r;
        const int rowoff = (i * (513 - i)) >> 1;
        const float ri = rsum[0][ty * 2 + r];
#pragma unroll
        for (int q = 0; q < 4; ++q) {
            const int j = jbase + tx * 4 + q;
            if (!diag || j >= i) {
                float* p = &ob[rowoff + (j - i)];
                const float e = *p;
                *p = sc * (e - (ri + rsum[1][tx * 4 + q]) * (1.0f / 256.0f));
            }
        }
    }
}

extern "C" void kernel_launch(void* const* d_in, const int* in_sizes, int n_in,
                              void* d_out, int out_size, void* d_ws, size_t ws_size,
                              hipStream_t stream) {
    const float* feat = (const float*)d_in[0];
    const float* temp = (const float*)d_in[1];
    float* out = (float*)d_out;
    float* rsp = (float*)d_ws;          // 64*4*4*64 floats = 256 KB slots

    tile_kernel<<<NB * 10, 512, 0, stream>>>(feat, rsp, out);
    center_kernel<<<NB * 10, 512, 0, stream>>>(temp, rsp, out);
}